// Round 1
// baseline (4942.723 us; speedup 1.0000x reference)
//
#include <hip/hip_runtime.h>
#include <math.h>

// Problem constants (fixed by the reference module)
#define HSZ   512
#define H4    2048
#define SEQ   64
#define VOC   32000
#define BEAM  3
#define TMAX  50

__device__ __forceinline__ float wsum(float v) {
#pragma unroll
  for (int off = 32; off; off >>= 1) v += __shfl_xor(v, off, 64);
  return v;
}
__device__ __forceinline__ float dot4(float4 a, float4 b) {
  return a.x * b.x + a.y * b.y + a.z * b.z + a.w * b.w;
}
__device__ __forceinline__ float sigf(float x) { return 1.f / (1.f + expf(-x)); }

__device__ __forceinline__ bool better(float v1, int i1, float v2, int i2) {
  return (v1 > v2) || (v1 == v2 && i1 < i2);  // jax.lax.top_k order: value desc, index asc
}
__device__ __forceinline__ void ins3(float* v, int* idx, float nv, int ni) {
  if (better(nv, ni, v[2], idx[2])) {
    if (better(nv, ni, v[1], idx[1])) {
      v[2] = v[1]; idx[2] = idx[1];
      if (better(nv, ni, v[0], idx[0])) { v[1] = v[0]; idx[1] = idx[0]; v[0] = nv; idx[0] = ni; }
      else { v[1] = nv; idx[1] = ni; }
    } else { v[2] = nv; idx[2] = ni; }
  }
}

// ---------------- encoder ----------------

// blocks 0..63: gather embeddings of input tokens; blocks 64..67: zero initial h/c rows
__global__ void k_init_enc(const int* __restrict__ seq, const float* __restrict__ emb,
                           float* __restrict__ emb_seq, float* __restrict__ h1a,
                           float* __restrict__ c1a, float* __restrict__ h2a,
                           float* __restrict__ c2a) {
  int b = blockIdx.x;
  if (b < 64) {
    int tok = seq[b];
    for (int e = threadIdx.x; e < HSZ; e += 256) emb_seq[b * HSZ + e] = emb[tok * HSZ + e];
  } else {
    float* p = (b == 64) ? h1a : (b == 65) ? c1a : (b == 66) ? h2a : c2a;
    for (int e = threadIdx.x; e < HSZ; e += 256) p[e] = 0.f;
  }
}

// xp[t][r] = bias[r] + dot(W[r], X[t])   (t in [0,64), r in [0,2048))  grid=512 x 256
__global__ void k_xw1(const float* __restrict__ W, const float* __restrict__ bias,
                      const float* __restrict__ X, float* __restrict__ out) {
  int t  = threadIdx.x & 63;
  int rl = threadIdx.x >> 6;
  int r  = blockIdx.x * 4 + rl;
  const float* wr = W + r * HSZ;
  const float* xr = X + t * HSZ;
  float acc = 0.f;
  for (int e = 0; e < HSZ; e += 4) {
    float4 wv = *(const float4*)(wr + e);
    float4 xv = *(const float4*)(xr + e);
    acc += dot4(wv, xv);
  }
  out[t * H4 + r] = acc + bias[r];
}

// One wavefront slot: layer1 cell t=s (blocks 0..127), layer2 cell t=s-1 (blocks 128..255).
// h*a rows: row t = state after t steps (row 0 = zeros); cell t reads row t, writes row t+1.
__global__ void k_encslot(const float* __restrict__ Whh1, const float* __restrict__ xp1,
                          const float* __restrict__ Wih2, const float* __restrict__ Whh2,
                          const float* __restrict__ b2, float* __restrict__ h1a,
                          float* __restrict__ c1a, float* __restrict__ h2a,
                          float* __restrict__ c2a, int s) {
  int wave = __builtin_amdgcn_readfirstlane((int)(threadIdx.x >> 6));
  int lane = threadIdx.x & 63;
  bool l2  = blockIdx.x >= 128;
  int t    = l2 ? s - 1 : s;
  if (t < 0 || t >= SEQ) return;
  int j = ((int)blockIdx.x - (l2 ? 128 : 0)) * 4 + wave;  // 0..511
  float z[4];
  if (!l2) {
    const float4* h = (const float4*)(h1a + t * HSZ);
    float4 h0 = h[lane], h1v = h[lane + 64];
#pragma unroll
    for (int g = 0; g < 4; ++g) {
      int row = j + (g << 9);
      const float4* wr = (const float4*)(Whh1 + row * HSZ);
      float acc = dot4(wr[lane], h0) + dot4(wr[lane + 64], h1v);
      z[g] = wsum(acc) + xp1[t * H4 + row];
    }
    if (lane == 0) {
      float c = sigf(z[1]) * c1a[t * HSZ + j] + sigf(z[0]) * tanhf(z[2]);
      c1a[(t + 1) * HSZ + j] = c;
      h1a[(t + 1) * HSZ + j] = sigf(z[3]) * tanhf(c);
    }
  } else {
    const float4* x = (const float4*)(h1a + (t + 1) * HSZ);  // layer1 output at time t
    const float4* h = (const float4*)(h2a + t * HSZ);
    float4 x0 = x[lane], x1 = x[lane + 64], h0 = h[lane], h1v = h[lane + 64];
#pragma unroll
    for (int g = 0; g < 4; ++g) {
      int row = j + (g << 9);
      const float4* wi = (const float4*)(Wih2 + row * HSZ);
      const float4* wh = (const float4*)(Whh2 + row * HSZ);
      float acc = dot4(wi[lane], x0) + dot4(wi[lane + 64], x1) +
                  dot4(wh[lane], h0) + dot4(wh[lane + 64], h1v);
      z[g] = wsum(acc) + b2[row];
    }
    if (lane == 0) {
      float c = sigf(z[1]) * c2a[t * HSZ + j] + sigf(z[0]) * tanhf(z[2]);
      c2a[(t + 1) * HSZ + j] = c;
      h2a[(t + 1) * HSZ + j] = sigf(z[3]) * tanhf(c);
    }
  }
}

// ---------------- decoder ----------------

__global__ void k_dinit(const float* __restrict__ h1a, const float* __restrict__ c1a,
                        const float* __restrict__ h2a, const float* __restrict__ c2a,
                        float* __restrict__ hd, float* __restrict__ cd,
                        float* __restrict__ x_dec, const float* __restrict__ emb_dec,
                        const int* __restrict__ bosp) {
  int bos = bosp[0];
  for (int e = threadIdx.x; e < HSZ; e += 256) {
    hd[e]          = h1a[SEQ * HSZ + e];
    cd[e]          = c1a[SEQ * HSZ + e];
    hd[1536 + e]   = h2a[SEQ * HSZ + e];
    cd[1536 + e]   = c2a[SEQ * HSZ + e];
    x_dec[e]       = emb_dec[bos * HSZ + e];
  }
}

// one LSTM cell, B beams; grid=128 x 256 (512 waves, wave j owns gate-group j)
template <int B>
__global__ void k_dcell(const float* __restrict__ Wih, const float* __restrict__ Whh,
                        const float* __restrict__ bias, const float* __restrict__ x,
                        const float* __restrict__ hin, const float* __restrict__ cin,
                        float* __restrict__ hout, float* __restrict__ cout) {
  int wave = __builtin_amdgcn_readfirstlane((int)(threadIdx.x >> 6));
  int lane = threadIdx.x & 63;
  int j = blockIdx.x * 4 + wave;
  float4 xv[B][2], hv[B][2];
#pragma unroll
  for (int b = 0; b < B; ++b) {
    const float4* xb = (const float4*)(x + b * HSZ);
    const float4* hb = (const float4*)(hin + b * HSZ);
    xv[b][0] = xb[lane]; xv[b][1] = xb[lane + 64];
    hv[b][0] = hb[lane]; hv[b][1] = hb[lane + 64];
  }
  float z[4][B];
#pragma unroll
  for (int g = 0; g < 4; ++g) {
    int row = j + (g << 9);
    const float4* wi = (const float4*)(Wih + row * HSZ);
    const float4* wh = (const float4*)(Whh + row * HSZ);
    float4 wi0 = wi[lane], wi1 = wi[lane + 64], wh0 = wh[lane], wh1 = wh[lane + 64];
    float bb = bias[row];
#pragma unroll
    for (int b = 0; b < B; ++b) {
      float acc = dot4(wi0, xv[b][0]) + dot4(wi1, xv[b][1]) +
                  dot4(wh0, hv[b][0]) + dot4(wh1, hv[b][1]);
      z[g][b] = wsum(acc) + bb;
    }
  }
  if (lane == 0) {
#pragma unroll
    for (int b = 0; b < B; ++b) {
      float c = sigf(z[1][b]) * cin[b * HSZ + j] + sigf(z[0][b]) * tanhf(z[2][b]);
      cout[b * HSZ + j] = c;
      hout[b * HSZ + j] = sigf(z[3][b]) * tanhf(c);
    }
  }
}

// attention + context + concat; 1 block x 256
template <int B>
__global__ void k_att(const float* __restrict__ h2, const float* __restrict__ enc,
                      float* __restrict__ xc) {
  __shared__ float xs[B * HSZ];
  __shared__ float at[B * SEQ];
  int tid = threadIdx.x;
  for (int i = tid; i < B * HSZ; i += 256) xs[i] = h2[i];
  __syncthreads();
  for (int i = tid; i < B * SEQ; i += 256) {
    int b = i >> 6, s2 = i & 63;
    const float* er = enc + (s2 + 1) * HSZ;
    const float* xb = xs + b * HSZ;
    float acc = 0.f;
    for (int e = 0; e < HSZ; e += 4) {
      float4 ev = *(const float4*)(er + e);
      acc += ev.x * xb[e] + ev.y * xb[e + 1] + ev.z * xb[e + 2] + ev.w * xb[e + 3];
    }
    at[i] = acc;
  }
  __syncthreads();
  if (tid < B) {
    float m = -INFINITY;
    for (int s2 = 0; s2 < SEQ; ++s2) m = fmaxf(m, at[tid * SEQ + s2]);
    float s = 0.f;
    for (int s2 = 0; s2 < SEQ; ++s2) { float e = expf(at[tid * SEQ + s2] - m); at[tid * SEQ + s2] = e; s += e; }
    float inv = 1.f / s;
    for (int s2 = 0; s2 < SEQ; ++s2) at[tid * SEQ + s2] *= inv;
  }
  __syncthreads();
  for (int i = tid; i < B * HSZ; i += 256) {
    int b = i >> 9, hcol = i & 511;
    float acc = 0.f;
    for (int s2 = 0; s2 < SEQ; ++s2) acc += at[b * SEQ + s2] * enc[(s2 + 1) * HSZ + hcol];
    xc[b * 1024 + hcol]       = xs[b * HSZ + hcol];
    xc[b * 1024 + 512 + hcol] = acc;
  }
}

// feat = tanh(xc @ W_c.T); grid=128 x 256
template <int B>
__global__ void k_feat(const float* __restrict__ Wc, const float* __restrict__ xc,
                       float* __restrict__ feat) {
  int wave = __builtin_amdgcn_readfirstlane((int)(threadIdx.x >> 6));
  int lane = threadIdx.x & 63;
  int j = blockIdx.x * 4 + wave;
  const float4* w = (const float4*)(Wc + j * 1024);
  float4 w0 = w[lane], w1 = w[lane + 64], w2 = w[lane + 128], w3 = w[lane + 192];
#pragma unroll
  for (int b = 0; b < B; ++b) {
    const float4* xb = (const float4*)(xc + b * 1024);
    float acc = dot4(w0, xb[lane]) + dot4(w1, xb[lane + 64]) +
                dot4(w2, xb[lane + 128]) + dot4(w3, xb[lane + 192]);
    acc = wsum(acc);
    if (lane == 0) feat[b * HSZ + j] = tanhf(acc);
  }
}

// logits + streaming (max, sumexp, top3) per beam per block; grid=256 x 256
template <int B>
__global__ void k_logits(const float* __restrict__ Wout, const float* __restrict__ bout,
                         const float* __restrict__ feat, float* __restrict__ pm,
                         float* __restrict__ ps, float* __restrict__ pv,
                         int* __restrict__ pi) {
  int tid  = threadIdx.x;
  int wave = __builtin_amdgcn_readfirstlane((int)(tid >> 6));
  int lane = tid & 63;
  int gid  = blockIdx.x * 4 + wave;  // 0..1023
  float4 f0[B], f1[B];
#pragma unroll
  for (int b = 0; b < B; ++b) {
    const float4* fb = (const float4*)(feat + b * HSZ);
    f0[b] = fb[lane]; f1[b] = fb[lane + 64];
  }
  float m[B], ss[B], tv[B][3];
  int tix[B][3];
#pragma unroll
  for (int b = 0; b < B; ++b) {
    m[b] = -INFINITY; ss[b] = 0.f;
#pragma unroll
    for (int k = 0; k < 3; ++k) { tv[b][k] = -INFINITY; tix[b][k] = 0x7fffffff; }
  }
  for (int v = gid; v < VOC; v += 1024) {
    const float4* wr = (const float4*)(Wout + v * HSZ);
    float4 w0 = wr[lane], w1 = wr[lane + 64];
    float bo = bout[v];
#pragma unroll
    for (int b = 0; b < B; ++b) {
      float acc = dot4(w0, f0[b]) + dot4(w1, f1[b]);
      acc = wsum(acc) + bo;             // all lanes hold the logit (uniform)
      float mo = m[b], mn = fmaxf(mo, acc);
      ss[b] = ss[b] * expf(mo - mn) + expf(acc - mn);
      m[b]  = mn;
      ins3(tv[b], tix[b], acc, v);
    }
  }
  __shared__ float lm[4][3], lss[4][3], lv[4][3][3];
  __shared__ int li[4][3][3];
  if (lane == 0) {
#pragma unroll
    for (int b = 0; b < B; ++b) {
      lm[wave][b] = m[b]; lss[wave][b] = ss[b];
#pragma unroll
      for (int k = 0; k < 3; ++k) { lv[wave][b][k] = tv[b][k]; li[wave][b][k] = tix[b][k]; }
    }
  }
  __syncthreads();
  if (tid < B) {
    int b = tid;
    float M = fmaxf(fmaxf(lm[0][b], lm[1][b]), fmaxf(lm[2][b], lm[3][b]));
    float S = 0.f;
#pragma unroll
    for (int w2 = 0; w2 < 4; ++w2) S += lss[w2][b] * expf(lm[w2][b] - M);
    float bv[3] = {-INFINITY, -INFINITY, -INFINITY};
    int bi3[3]  = {0x7fffffff, 0x7fffffff, 0x7fffffff};
#pragma unroll
    for (int w2 = 0; w2 < 4; ++w2)
#pragma unroll
      for (int k = 0; k < 3; ++k) ins3(bv, bi3, lv[w2][b][k], li[w2][b][k]);
    int o = blockIdx.x * 3 + b;
    pm[o] = M; ps[o] = S;
#pragma unroll
    for (int k = 0; k < 3; ++k) { pv[o * 3 + k] = bv[k]; pi[o * 3 + k] = bi3[k]; }
  }
}

// final merge + beam bookkeeping; 1 block x 256
template <int B, int STEP0>
__global__ void k_merge(const float* __restrict__ pm, const float* __restrict__ ps,
                        const float* __restrict__ pv, const int* __restrict__ pi,
                        const float* __restrict__ hdn, const float* __restrict__ cdn,
                        float* __restrict__ hd, float* __restrict__ cd,
                        int* __restrict__ bt, float* __restrict__ scores,
                        int* __restrict__ tokens, float* __restrict__ x_dec,
                        const float* __restrict__ emb_dec, const int* __restrict__ bosp,
                        int* __restrict__ outp, int ti) {
  __shared__ float sM[3], sS[3], sV[3][3], sScore[3];
  __shared__ int sI[3][3], sOrig[3], sTokNew[3], sTokOld[3], sKstar;
  int tid = threadIdx.x, wave = tid >> 6, lane = tid & 63;
  if (wave < B) {
    int b = wave;
    float lm4[4], ls4[4];
    float M = -INFINITY;
#pragma unroll
    for (int q = 0; q < 4; ++q) {
      int blk = lane + q * 64;
      lm4[q] = pm[blk * 3 + b]; ls4[q] = ps[blk * 3 + b];
      M = fmaxf(M, lm4[q]);
    }
#pragma unroll
    for (int off = 32; off; off >>= 1) M = fmaxf(M, __shfl_xor(M, off, 64));
    float S = 0.f;
#pragma unroll
    for (int q = 0; q < 4; ++q) S += ls4[q] * expf(lm4[q] - M);
    S = wsum(S);
    float bv[3] = {-INFINITY, -INFINITY, -INFINITY};
    int bi3[3]  = {0x7fffffff, 0x7fffffff, 0x7fffffff};
#pragma unroll
    for (int q = 0; q < 4; ++q) {
      int blk = lane + q * 64;
#pragma unroll
      for (int k = 0; k < 3; ++k) ins3(bv, bi3, pv[(blk * 3 + b) * 3 + k], pi[(blk * 3 + b) * 3 + k]);
    }
#pragma unroll
    for (int off = 32; off; off >>= 1) {
      float ov[3]; int oi[3];
#pragma unroll
      for (int k = 0; k < 3; ++k) { ov[k] = __shfl_xor(bv[k], off, 64); oi[k] = __shfl_xor(bi3[k], off, 64); }
#pragma unroll
      for (int k = 0; k < 3; ++k) ins3(bv, bi3, ov[k], oi[k]);
    }
    if (lane == 0) {
      sM[b] = M; sS[b] = S;
#pragma unroll
      for (int k = 0; k < 3; ++k) { sV[b][k] = bv[k]; sI[b][k] = bi3[k]; }
    }
  }
  __syncthreads();
  if (tid == 0) {
    if (STEP0) {
      float off0 = -sM[0] - logf(sS[0]);
      for (int k = 0; k < 3; ++k) {
        sScore[k] = sV[0][k] + off0;
        sTokNew[k] = sI[0][k]; sOrig[k] = 0; sTokOld[k] = 0;
        scores[k] = sScore[k]; tokens[k] = sTokNew[k];
      }
    } else {
      float osc[3]; int otk[3];
      for (int b = 0; b < 3; ++b) { osc[b] = scores[b]; otk[b] = tokens[b]; sTokOld[b] = otk[b]; }
      float cum[9];
      for (int b = 0; b < 3; ++b) {
        float o = osc[b] - sM[b] - logf(sS[b]);
        for (int k = 0; k < 3; ++k) cum[b * 3 + k] = sV[b][k] + o;
      }
      bool used[9] = {false, false, false, false, false, false, false, false, false};
      for (int k = 0; k < 3; ++k) {
        int bf = 0; float bb = -INFINITY;
        for (int f = 0; f < 9; ++f)
          if (!used[f] && cum[f] > bb) { bb = cum[f]; bf = f; }   // strict > keeps lowest flat idx on tie
        used[bf] = true;
        sScore[k] = bb;
        int ob = bf / 3;
        sOrig[k] = ob;
        sTokNew[k] = sI[ob][bf - ob * 3];
      }
      for (int k = 0; k < 3; ++k) { scores[k] = sScore[k]; tokens[k] = sTokNew[k]; }
    }
    float bb = -INFINITY; int kk = 0;
    for (int k = 0; k < 3; ++k) if (sScore[k] > bb) { bb = sScore[k]; kk = k; }
    sKstar = kk;
  }
  __syncthreads();
  // permute h,c into current-state buffers for next step
  for (int idx = tid; idx < 2 * 3 * HSZ; idx += 256) {
    int l = idx / 1536, rem = idx % 1536, k = rem / HSZ, e = rem & 511;
    int o = STEP0 ? 0 : sOrig[k];
    hd[l * 1536 + k * HSZ + e] = hdn[l * 1536 + o * HSZ + e];
    cd[l * 1536 + k * HSZ + e] = cdn[l * 1536 + o * HSZ + e];
  }
  if (STEP0) {
    int bos = bosp[0];
    for (int idx = tid; idx < BEAM * TMAX; idx += 256) bt[idx] = bos;  // buffer 0
  } else {
    const int* src = bt + (ti & 1) * (BEAM * TMAX);
    int* dst = bt + ((ti + 1) & 1) * (BEAM * TMAX);
    for (int idx = tid; idx < BEAM * TMAX; idx += 256) {
      int k = idx / TMAX, jj = idx % TMAX, o = sOrig[k];
      dst[idx] = (jj == ti + 1) ? sTokOld[o] : src[o * TMAX + jj];
    }
  }
  for (int idx = tid; idx < BEAM * HSZ; idx += 256) {
    int k = idx >> 9, e = idx & 511;
    x_dec[idx] = emb_dec[sTokNew[k] * HSZ + e];
  }
  if (!STEP0 && ti == TMAX - 2) {
    __syncthreads();
    const int* dst = bt + ((ti + 1) & 1) * (BEAM * TMAX);
    for (int jj = tid; jj < TMAX; jj += 256) outp[jj] = dst[sKstar * TMAX + jj];
  }
}

extern "C" void kernel_launch(void* const* d_in, const int* in_sizes, int n_in,
                              void* d_out, int out_size, void* d_ws, size_t ws_size,
                              hipStream_t stream) {
  const int*   seq     = (const int*)d_in[0];
  const float* emb_enc = (const float*)d_in[1];
  const float* Wih_enc = (const float*)d_in[2];
  const float* Whh_enc = (const float*)d_in[3];
  const float* b_enc   = (const float*)d_in[4];
  const float* emb_dec = (const float*)d_in[5];
  const float* Wih_dec = (const float*)d_in[6];
  const float* Whh_dec = (const float*)d_in[7];
  const float* b_dec   = (const float*)d_in[8];
  const float* W_c     = (const float*)d_in[9];
  const float* W_out   = (const float*)d_in[10];
  const float* b_out   = (const float*)d_in[11];
  const int*   bosp    = (const int*)d_in[14];

  float* w = (float*)d_ws;
  float* emb_seq = w; w += SEQ * HSZ;
  float* xp1     = w; w += SEQ * H4;
  float* h1a     = w; w += (SEQ + 1) * HSZ;
  float* c1a     = w; w += (SEQ + 1) * HSZ;
  float* h2a     = w; w += (SEQ + 1) * HSZ;
  float* c2a     = w; w += (SEQ + 1) * HSZ;
  float* hd      = w; w += 2 * BEAM * HSZ;
  float* cd      = w; w += 2 * BEAM * HSZ;
  float* hdn     = w; w += 2 * BEAM * HSZ;
  float* cdn     = w; w += 2 * BEAM * HSZ;
  float* x_dec   = w; w += BEAM * HSZ;
  float* xc      = w; w += BEAM * 1024;
  float* feat    = w; w += BEAM * HSZ;
  float* pm      = w; w += 256 * 3;
  float* ps      = w; w += 256 * 3;
  float* pv      = w; w += 256 * 3 * 3;
  float* scoresB = w; w += 4;
  int* pi     = (int*)w; w += 256 * 3 * 3;
  int* tokens = (int*)w; w += 4;
  int* bt     = (int*)w; w += 2 * BEAM * TMAX + 4;

  const size_t LOFF = (size_t)H4 * HSZ;  // per-layer weight stride

  k_init_enc<<<68, 256, 0, stream>>>(seq, emb_enc, emb_seq, h1a, c1a, h2a, c2a);
  k_xw1<<<512, 256, 0, stream>>>(Wih_enc, b_enc, emb_seq, xp1);
  for (int s = 0; s <= SEQ; ++s)
    k_encslot<<<256, 256, 0, stream>>>(Whh_enc, xp1, Wih_enc + LOFF, Whh_enc + LOFF,
                                       b_enc + H4, h1a, c1a, h2a, c2a, s);
  k_dinit<<<1, 256, 0, stream>>>(h1a, c1a, h2a, c2a, hd, cd, x_dec, emb_dec, bosp);

  for (int step = 0; step < TMAX; ++step) {
    int ti = step - 1;
    if (step == 0) {
      k_dcell<1><<<128, 256, 0, stream>>>(Wih_dec, Whh_dec, b_dec, x_dec, hd, cd, hdn, cdn);
      k_dcell<1><<<128, 256, 0, stream>>>(Wih_dec + LOFF, Whh_dec + LOFF, b_dec + H4,
                                          hdn, hd + 1536, cd + 1536, hdn + 1536, cdn + 1536);
      k_att<1><<<1, 256, 0, stream>>>(hdn + 1536, h2a, xc);
      k_feat<1><<<128, 256, 0, stream>>>(W_c, xc, feat);
      k_logits<1><<<256, 256, 0, stream>>>(W_out, b_out, feat, pm, ps, pv, pi);
      k_merge<1, 1><<<1, 256, 0, stream>>>(pm, ps, pv, pi, hdn, cdn, hd, cd, bt, scoresB,
                                           tokens, x_dec, emb_dec, bosp, (int*)d_out, ti);
    } else {
      k_dcell<3><<<128, 256, 0, stream>>>(Wih_dec, Whh_dec, b_dec, x_dec, hd, cd, hdn, cdn);
      k_dcell<3><<<128, 256, 0, stream>>>(Wih_dec + LOFF, Whh_dec + LOFF, b_dec + H4,
                                          hdn, hd + 1536, cd + 1536, hdn + 1536, cdn + 1536);
      k_att<3><<<1, 256, 0, stream>>>(hdn + 1536, h2a, xc);
      k_feat<3><<<128, 256, 0, stream>>>(W_c, xc, feat);
      k_logits<3><<<256, 256, 0, stream>>>(W_out, b_out, feat, pm, ps, pv, pi);
      k_merge<3, 0><<<1, 256, 0, stream>>>(pm, ps, pv, pi, hdn, cdn, hd, cd, bt, scoresB,
                                           tokens, x_dec, emb_dec, bosp, (int*)d_out, ti);
    }
  }
}